// Round 11
// baseline (82.495 us; speedup 1.0000x reference)
//
#include <hip/hip_runtime.h>

#define IMG     512
#define VALID   506          // IMG - 6
#define NPLANES 96           // 32 * 3
#define R       10           // output rows per wave-band
#define NBANDS  51           // 51*10 = 510 >= 506 (slot 51 = pad)

struct Q { float4 x0, x1, y0, y1; };

__device__ __forceinline__ float shfl_next(float v, int baddr) {
    return __int_as_float(__builtin_amdgcn_ds_bpermute(baddr, __float_as_int(v)));
}

__device__ __forceinline__ void addv(float4& V, const float4 p) {
    V.x += p.x; V.y += p.y; V.z += p.z; V.w += p.w;
}
__device__ __forceinline__ void subv(float4& V, const float4 p) {
    V.x -= p.x; V.y -= p.y; V.z -= p.z; V.w -= p.w;
}
__device__ __forceinline__ void addmul(float4& V, const float4 p, const float4 q) {
    V.x = fmaf(p.x, q.x, V.x); V.y = fmaf(p.y, q.y, V.y);
    V.z = fmaf(p.z, q.z, V.z); V.w = fmaf(p.w, q.w, V.w);
}
__device__ __forceinline__ void submul(float4& V, const float4 p, const float4 q) {
    V.x = fmaf(-p.x, q.x, V.x); V.y = fmaf(-p.y, q.y, V.y);
    V.z = fmaf(-p.z, q.z, V.z); V.w = fmaf(-p.w, q.w, V.w);
}

// NOTE: plain __launch_bounds__(128). Any (N, minwaves) form pins VGPR=64 on
// this compiler (R5/R7/R8: 257-964 MB scratch spill). Never add the 2nd arg.
__global__ __launch_bounds__(128) void ssim_wave_kernel(
    const float* __restrict__ pred,
    const float* __restrict__ target,
    double* __restrict__ accum)
{
    const int t     = threadIdx.x;
    const int lane  = t & 63;
    const int wv    = t >> 6;
    const int band  = blockIdx.y * 2 + wv;      // 0..51 (51 = pad)
    const int plane = blockIdx.x;               // plane-major: plane p -> XCD p%8
    const int row0  = band * R;
    const int col   = lane << 3;                // this lane's 8 columns

    if (row0 >= VALID) return;                  // pad band: kernel is barrier-free

    const size_t pbase = (size_t)plane * (IMG * IMG);
    const float* __restrict__ pp = pred   + pbase + col;
    const float* __restrict__ pt = target + pbase + col;

    const int baddr = ((lane + 1) & 63) << 2;   // ds_bpermute addr: lane+1

    float4 z = make_float4(0.f, 0.f, 0.f, 0.f);
    float4 Vx_a = z, Vx_b = z, Vy_a = z, Vy_b = z;
    float4 Vss_a = z, Vss_b = z, Vxy_a = z, Vxy_b = z;   // Vss = Vxx + Vyy merged

#define LOADQ(q, r) do { int _rr = (r) < (IMG - 1) ? (r) : (IMG - 1);             \
    const float4* _p  = reinterpret_cast<const float4*>(pp + (size_t)_rr * IMG); \
    const float4* _q2 = reinterpret_cast<const float4*>(pt + (size_t)_rr * IMG); \
    q.x0 = _p[0]; q.x1 = _p[1]; q.y0 = _q2[0]; q.y1 = _q2[1]; } while (0)

#define ACCQ(q) do {                                                        \
    addv(Vx_a, q.x0); addv(Vx_b, q.x1); addv(Vy_a, q.y0); addv(Vy_b, q.y1); \
    addmul(Vss_a, q.x0, q.x0); addmul(Vss_b, q.x1, q.x1);                   \
    addmul(Vss_a, q.y0, q.y0); addmul(Vss_b, q.y1, q.y1);                   \
    addmul(Vxy_a, q.x0, q.y0); addmul(Vxy_b, q.x1, q.y1); } while (0)

#define SUBQ(q) do {                                                        \
    subv(Vx_a, q.x0); subv(Vx_b, q.x1); subv(Vy_a, q.y0); subv(Vy_b, q.y1); \
    submul(Vss_a, q.x0, q.x0); submul(Vss_b, q.x1, q.x1);                   \
    submul(Vss_a, q.y0, q.y0); submul(Vss_b, q.y1, q.y1);                   \
    submul(Vxy_a, q.x0, q.y0); submul(Vxy_b, q.x1, q.y1); } while (0)

    const float c1 = 0.9604f;   // (0.01*2)^2 * 49^2
    const float c2 = 8.4672f;   // (0.03*2)^2 * 48*49
    float local = 0.f;

    // SSIM from the 4 sliding window sums (ox, oy, oss, oxy live in regs)
#define SSIM_PX() do {                                                 \
    float t1 = ox * oy;                                                \
    float t2 = fmaf(ox, ox, oy * oy);                                  \
    float n1 = fmaf(2.f, t1, c1);                                      \
    float d1 = t2 + c1;                                                \
    float n2 = fmaf(-2.f, t1, fmaf(98.f, oxy, c2));                    \
    float d2 = fmaf(49.f, oss, c2) - t2;                               \
    S = __fdividef(n1 * n2, d1 * d2); } while (0)

    // slide one column: new halo element (from lane+1, literal component)
    // enters, own literal component leaves. All indices static.
#define HS_STEP(NEWC_X, NEWC_Y, NEWC_SS, NEWC_XY, OLDC_X, OLDC_Y, OLDC_SS, OLDC_XY) do { \
    float nx = shfl_next(NEWC_X,  baddr);                              \
    float ny = shfl_next(NEWC_Y,  baddr);                              \
    float ns = shfl_next(NEWC_SS, baddr);                              \
    float nq = shfl_next(NEWC_XY, baddr);                              \
    ox  += nx - (OLDC_X);  oy  += ny - (OLDC_Y);                       \
    oss += ns - (OLDC_SS); oxy += nq - (OLDC_XY); } while (0)

    // pixel-major horizontal 7-tap + SSIM for one output row (8 px/lane)
#define HSSIM(i) do { if ((row0 + (i)) < VALID) {                      \
    float S;                                                           \
    float ox  = ((Vx_a.x + Vx_a.y) + (Vx_a.z + Vx_a.w)) + ((Vx_b.x + Vx_b.y) + Vx_b.z);       \
    float oy  = ((Vy_a.x + Vy_a.y) + (Vy_a.z + Vy_a.w)) + ((Vy_b.x + Vy_b.y) + Vy_b.z);       \
    float oss = ((Vss_a.x + Vss_a.y) + (Vss_a.z + Vss_a.w)) + ((Vss_b.x + Vss_b.y) + Vss_b.z);\
    float oxy = ((Vxy_a.x + Vxy_a.y) + (Vxy_a.z + Vxy_a.w)) + ((Vxy_b.x + Vxy_b.y) + Vxy_b.z);\
    SSIM_PX(); local += S;                       /* j=0: col<=504 always valid */ \
    ox  += Vx_b.w  - Vx_a.x;  oy  += Vy_b.w  - Vy_a.x;                 \
    oss += Vss_b.w - Vss_a.x; oxy += Vxy_b.w - Vxy_a.x;                \
    SSIM_PX(); local += S;                       /* j=1: col+1<=505 always valid */ \
    HS_STEP(Vx_a.x, Vy_a.x, Vss_a.x, Vxy_a.x, Vx_a.y, Vy_a.y, Vss_a.y, Vxy_a.y); \
    SSIM_PX(); local += (col + 2 < VALID) ? S : 0.f;                   \
    HS_STEP(Vx_a.y, Vy_a.y, Vss_a.y, Vxy_a.y, Vx_a.z, Vy_a.z, Vss_a.z, Vxy_a.z); \
    SSIM_PX(); local += (col + 3 < VALID) ? S : 0.f;                   \
    HS_STEP(Vx_a.z, Vy_a.z, Vss_a.z, Vxy_a.z, Vx_a.w, Vy_a.w, Vss_a.w, Vxy_a.w); \
    SSIM_PX(); local += (col + 4 < VALID) ? S : 0.f;                   \
    HS_STEP(Vx_a.w, Vy_a.w, Vss_a.w, Vxy_a.w, Vx_b.x, Vy_b.x, Vss_b.x, Vxy_b.x); \
    SSIM_PX(); local += (col + 5 < VALID) ? S : 0.f;                   \
    HS_STEP(Vx_b.x, Vy_b.x, Vss_b.x, Vxy_b.x, Vx_b.y, Vy_b.y, Vss_b.y, Vxy_b.y); \
    SSIM_PX(); local += (col + 6 < VALID) ? S : 0.f;                   \
    HS_STEP(Vx_b.y, Vy_b.y, Vss_b.y, Vxy_b.y, Vx_b.z, Vy_b.z, Vss_b.z, Vxy_b.z); \
    SSIM_PX(); local += (col + 7 < VALID) ? S : 0.f;                   \
    } } while (0)

    // ---- 3 slots: NA/NB new-row ping-pong (issue->consume distance 2 iters),
    //      OL old-row (distance 1, L2-hot). Consume-then-reissue in place ->
    //      counted vmcnt waits, pipeline never drains. (R9 schedule, slimmed.)
    Q NA, NB, OL;

    // ---- prologue: rows r0..r0+5 accumulated; 3 load-batches always in flight
    LOADQ(NA, row0 + 0); LOADQ(NB, row0 + 1); LOADQ(OL, row0 + 2);
    ACCQ(NA); LOADQ(NA, row0 + 3);
    ACCQ(NB); LOADQ(NB, row0 + 4);
    ACCQ(OL); LOADQ(OL, row0 + 5);
    ACCQ(NA); LOADQ(NA, row0 + 6);   // iter-0 new row
    ACCQ(NB); LOADQ(NB, row0 + 7);   // iter-1 new row
    ACCQ(OL); LOADQ(OL, row0 + 0);   // iter-1 old row (reload, L2-hot)

    // ---- main: iter i consumes new row r0+6+i, subtracts r0+i-1;
    //      reissues OL <- r0+i (for iter i+1) and Nslot <- r0+8+i (for iter i+2)
#define STEP(Nslot, i) do {                                            \
    ACCQ(Nslot);                                                       \
    if ((i) >= 1) SUBQ(OL);                                            \
    if ((i) + 1 < R) LOADQ(OL, row0 + (i));                            \
    if ((i) + 2 < R) LOADQ(Nslot, row0 + 8 + (i));                     \
    HSSIM(i); } while (0)

    STEP(NA, 0);  STEP(NB, 1);  STEP(NA, 2);  STEP(NB, 3);
    STEP(NA, 4);  STEP(NB, 5);  STEP(NA, 6);  STEP(NB, 7);
    STEP(NA, 8);  STEP(NB, 9);

    // per-wave reduce -> one atomic per wave, scattered per plane (no barriers)
    #pragma unroll
    for (int off = 32; off > 0; off >>= 1)
        local += __shfl_down(local, off, 64);
    if (lane == 0)
        atomicAdd(&accum[plane], (double)local);
}

__global__ void ssim_finalize_kernel(const double* __restrict__ accum,
                                     float* __restrict__ out)
{
    const int l = threadIdx.x;           // 64 threads = 1 wave
    double s = accum[l];
    if (l < NPLANES - 64) s += accum[64 + l];
    #pragma unroll
    for (int off = 32; off > 0; off >>= 1)
        s += __shfl_down(s, off, 64);
    if (l == 0) {
        const double n_valid = (double)NPLANES * (double)VALID * (double)VALID;
        out[0] = (float)(1.0 - s / n_valid);
    }
}

extern "C" void kernel_launch(void* const* d_in, const int* in_sizes, int n_in,
                              void* d_out, int out_size, void* d_ws, size_t ws_size,
                              hipStream_t stream) {
    const float* pred   = (const float*)d_in[0];
    const float* target = (const float*)d_in[1];
    float* out = (float*)d_out;
    double* accum = (double*)d_ws;

    hipMemsetAsync(d_ws, 0, NPLANES * sizeof(double), stream);

    // 96 x 26 grid of 128-thread (2-wave) blocks; 2-wave granularity packs
    // 9-10 blocks/CU at VGPR ~100 -> ~one residency generation (2496 blocks).
    dim3 grid(NPLANES, (NBANDS + 2) / 2);
    ssim_wave_kernel<<<grid, 128, 0, stream>>>(pred, target, accum);
    ssim_finalize_kernel<<<1, 64, 0, stream>>>(accum, out);
}